// Round 10
// baseline (1618.148 us; speedup 1.0000x reference)
//
#include <hip/hip_runtime.h>
#include <math.h>

#define TKN 2048
#define DIM 1024
#define NHEAD 16
#define HDIM 64
#define HFF 2048
#define NE 8
#define TOPK 2
#define NCLS 10
#define NLAYER 4
#define SEQ 256
#define BATCH 8
#define CAP 2048  // fixed per-expert slot capacity (max tokens per expert)

typedef __attribute__((ext_vector_type(8))) _Float16 f16x8;
typedef __attribute__((ext_vector_type(4))) float f32x4;
typedef __attribute__((ext_vector_type(16))) float f32x16;
typedef __attribute__((ext_vector_type(8))) unsigned short u16x8;

__device__ __forceinline__ unsigned short f2h(float v) {
  _Float16 h = (_Float16)v;
  return __builtin_bit_cast(unsigned short, h);
}
__device__ __forceinline__ void fsplit(float v, unsigned short& hi, unsigned short& lo) {
  _Float16 h = (_Float16)v;
  hi = __builtin_bit_cast(unsigned short, h);
  lo = f2h(v - (float)h);
}
__device__ __forceinline__ void split8(float4 f0, float4 f1, f16x8& h, f16x8& l) {
  float fv[8] = {f0.x, f0.y, f0.z, f0.w, f1.x, f1.y, f1.z, f1.w};
#pragma unroll
  for (int i = 0; i < 8; ++i) {
    _Float16 hh = (_Float16)fv[i];
    h[i] = hh;
    l[i] = (_Float16)(fv[i] - (float)hh);
  }
}

__device__ __forceinline__ void gload_lds16(const void* g, void* l) {
  __builtin_amdgcn_global_load_lds((__attribute__((address_space(1))) void*)g,
                                   (__attribute__((address_space(3))) void*)l,
                                   16, 0, 0);
}

// ---------------- embed + positional encoding; also zeroes routing counters ----------
__global__ __launch_bounds__(256) void k_embed(const int* __restrict__ src,
                                               const float* __restrict__ emb,
                                               float* __restrict__ x,
                                               unsigned short* __restrict__ xhi,
                                               unsigned short* __restrict__ xlo,
                                               int* __restrict__ cnt_all) {
  const int t = blockIdx.x;
  const int tid = threadIdx.x;
  if (t == 0 && tid < NLAYER * NE) cnt_all[tid] = 0;
  const int b = t / SEQ;
  const int tok = src[t];
  const float* erow = emb + (size_t)tok * DIM;
  const size_t base = (size_t)t * DIM;
  const float cexp = -9.210340371976184f / 1024.0f;  // -ln(10000)/D
#pragma unroll
  for (int j = 0; j < 4; ++j) {
    int d = tid + 256 * j;
    int i2 = d & ~1;
    float ang = (float)b * expf((float)i2 * cexp);
    float pe = (d & 1) ? cosf(ang) : sinf(ang);
    float v = erow[d] * 32.0f + pe;
    x[base + d] = v;
    fsplit(v, xhi[base + d], xlo[base + d]);
  }
}

// ---------------- fp32 -> f16 hi/lo planes; two tensors in one dispatch ----------------
template <bool LO>
__global__ __launch_bounds__(256) void k_cvt_split2(const float* __restrict__ inA,
                                                    unsigned short* __restrict__ hA,
                                                    unsigned short* __restrict__ lA,
                                                    int n4A,
                                                    const float* __restrict__ inB,
                                                    unsigned short* __restrict__ hB,
                                                    unsigned short* __restrict__ lB) {
  int i = blockIdx.x * 256 + threadIdx.x;
  const float* in;
  unsigned short *oh, *ol;
  int j;
  if (i < n4A) { in = inA; oh = hA; ol = lA; j = i; }
  else         { in = inB; oh = hB; ol = lB; j = i - n4A; }
  float4 v = ((const float4*)in)[j];
  ushort4 h, l;
  fsplit(v.x, h.x, l.x); fsplit(v.y, h.y, l.y);
  fsplit(v.z, h.z, l.z); fsplit(v.w, h.w, l.w);
  ((ushort4*)oh)[j] = h;
  if (LO) ((ushort4*)ol)[j] = l;
}

// ---------------- transpose+split BOTH expert weights in one dispatch -----------------
// z < NE: w1[e] [DIM][HFF] -> w1t [HFF][DIM].  z >= NE: w2[e-NE] [HFF][DIM] -> [DIM][HFF].
template <bool LO>
__global__ __launch_bounds__(256) void k_cvt_t2_w12(
    const float* __restrict__ w1, unsigned short* __restrict__ o1h, unsigned short* __restrict__ o1l,
    const float* __restrict__ w2, unsigned short* __restrict__ o2h, unsigned short* __restrict__ o2l) {
  __shared__ float ts[64][33];
  const int t = threadIdx.x;
  const int z = blockIdx.z;
  const float* in;
  unsigned short *ohi, *olo;
  int R, Cc, bx, by;
  if (z < NE) {
    in = w1 + (size_t)z * DIM * HFF;
    ohi = o1h + (size_t)z * DIM * HFF;
    olo = o1l + (size_t)z * DIM * HFF;
    R = DIM; Cc = HFF; bx = blockIdx.x; by = blockIdx.y;   // 64 x 16
  } else {
    int e = z - NE;
    in = w2 + (size_t)e * HFF * DIM;
    ohi = o2h + (size_t)e * HFF * DIM;
    olo = o2l + (size_t)e * HFF * DIM;
    R = HFF; Cc = DIM;
    int id = blockIdx.y * 64 + blockIdx.x;                 // 0..1023
    bx = id & 31; by = id >> 5;                            // 32 x 32
  }
  const int c0 = bx * 32, r0 = by * 64;
  const int cc = t & 31, rr0 = t >> 5;
#pragma unroll
  for (int j = 0; j < 8; ++j)
    ts[rr0 + 8 * j][cc] = in[(size_t)(r0 + rr0 + 8 * j) * Cc + c0 + cc];
  __syncthreads();
  const int c = t >> 3, rch = (t & 7) * 8;
  u16x8 hv, lv;
#pragma unroll
  for (int i = 0; i < 8; ++i) {
    unsigned short hi, lo;
    fsplit(ts[rch + i][c], hi, lo);
    hv[i] = hi; lv[i] = lo;
  }
  size_t o = (size_t)(c0 + c) * R + r0 + rch;
  *(u16x8*)(ohi + o) = hv;
  if (LO) *(u16x8*)(olo + o) = lv;
}

// ---------------- compensated f16 MFMA GEMM (32x32x16), 4-wave blocks ----------
// MODE 0: dense. MODE 1: MoE gather (rows via slot_token). MODE 2: MoE contig (A=h).
// MoE: r0 = e*CAP (fixed stride), rows = cnt[e] (atomic routing, no route kernel).
// OUTK 0: fp32. 1: f16-hi. 2: f16 hi + lo.  SPLIT: 3-pass compensated.
// Wave computes 64x64 via 2x2 tiles of 32x32x16 (m101 C/D layout).
// LDS [128 rows][8 slots x 16B], phys_slot = slot ^ (row&7), pre-swizzled source.
// Dbuf + counted vmcnt: stage(t+1) -> vmcnt(8|4) -> barrier -> ds_read+MFMA -> barrier.
template <int MODE, bool RELU, int OUTK, bool SPLIT>
__global__ __launch_bounds__(256) void k_mfma_gemm(
    const unsigned short* __restrict__ Ahi, const unsigned short* __restrict__ Alo,
    const unsigned short* __restrict__ Bhi, const unsigned short* __restrict__ Blo,
    const float* __restrict__ bias, void* __restrict__ out0, void* __restrict__ out1,
    int M, int N, int K,
    const int* __restrict__ slot_token, const int* __restrict__ cnt) {
  constexpr int NP = SPLIT ? 2 : 1;
  __shared__ unsigned short U[2][NP][128 * 64];
  const int tid = threadIdx.x;
  const int w = tid >> 6, lane = tid & 63;
  const int bm = blockIdx.y * 128, bn = blockIdx.x * 128;
  int r0 = 0, rows = M, e = 0;
  if (MODE != 0) {
    e = blockIdx.z;
    r0 = e * CAP;
    rows = cnt[e];
    if (bm >= rows) return;
  }
  const size_t bwb = (size_t)e * K * N;
  const float* biasq = bias + (size_t)e * N;

  // staging: lane covers (row = w*32 + i*8 + (lane>>3), physical slot lane&7)
  const int lrow8 = lane >> 3;
  const int s = (lane & 7) ^ lrow8;
  const int chunk = (s & 3) * 8;
  const unsigned short* sp0[4];
  const unsigned short* sp1[4];
#pragma unroll
  for (int i = 0; i < 4; ++i) {
    int rloc = w * 32 + i * 8 + lrow8;
    int growA;
    if (MODE == 0) {
      growA = bm + rloc;
    } else {
      int rr = bm + rloc;
      if (rr >= rows) rr = rows - 1;
      growA = (MODE == 1) ? slot_token[r0 + rr] : (r0 + rr);
    }
    size_t aoff = (size_t)growA * K + chunk;
    size_t boff = bwb + (size_t)(bn + rloc) * K + chunk;
    if constexpr (SPLIT) {
      sp0[i] = (s < 4 ? Ahi : Alo) + aoff;
      sp1[i] = (s < 4 ? Bhi : Blo) + boff;
    } else {
      sp0[i] = (s < 4) ? (Ahi + aoff) : (Bhi + boff);
      sp1[i] = nullptr;
    }
  }

  f32x16 acc[2][2] = {};
  const int wr = w >> 1, wc = w & 1;
  const int l31 = lane & 31, kq = lane >> 5;
  const int sw = l31 & 7;
  unsigned aof[2][2], bof[2][2];
#pragma unroll
  for (int mt = 0; mt < 2; ++mt)
#pragma unroll
    for (int kh = 0; kh < 2; ++kh)
      aof[mt][kh] = (unsigned)((wr * 64 + mt * 32 + l31) * 64 + (((kh * 2 + kq) ^ sw) * 8));
#pragma unroll
  for (int nt = 0; nt < 2; ++nt)
#pragma unroll
    for (int kh = 0; kh < 2; ++kh)
      bof[nt][kh] = (unsigned)((wc * 64 + nt * 32 + l31) * 64 + (((kh * 2 + kq) ^ sw) * 8));

  // ---- prologue: issue tile-0 stage ----
#pragma unroll
  for (int i = 0; i < 4; ++i) {
    gload_lds16(sp0[i], &U[0][0][(w * 32 + i * 8) * 64]);
    sp0[i] += 32;
    if constexpr (SPLIT) {
      gload_lds16(sp1[i], &U[0][1][(w * 32 + i * 8) * 64]);
      sp1[i] += 32;
    }
  }

  const int NT = K / 32;
#pragma unroll 2
  for (int t = 0; t < NT; ++t) {
    const int cur = t & 1;
    if (t + 1 < NT) {
#pragma unroll
      for (int i = 0; i < 4; ++i) {
        gload_lds16(sp0[i], &U[cur ^ 1][0][(w * 32 + i * 8) * 64]);
        sp0[i] += 32;
        if constexpr (SPLIT) {
          gload_lds16(sp1[i], &U[cur ^ 1][1][(w * 32 + i * 8) * 64]);
          sp1[i] += 32;
        }
      }
      if constexpr (SPLIT)
        asm volatile("s_waitcnt vmcnt(8)" ::: "memory");
      else
        asm volatile("s_waitcnt vmcnt(4)" ::: "memory");
    } else {
      asm volatile("s_waitcnt vmcnt(0)" ::: "memory");
    }
    __builtin_amdgcn_s_barrier();

    f16x8 Ah[2][2], Bh[2][2], Al[2][2], Bl[2][2];
#pragma unroll
    for (int mt = 0; mt < 2; ++mt)
#pragma unroll
      for (int kh = 0; kh < 2; ++kh) {
        Ah[mt][kh] = *(const f16x8*)&U[cur][0][aof[mt][kh]];
        if constexpr (SPLIT) Al[mt][kh] = *(const f16x8*)&U[cur][0][aof[mt][kh] ^ 32];
      }
#pragma unroll
    for (int nt = 0; nt < 2; ++nt)
#pragma unroll
      for (int kh = 0; kh < 2; ++kh) {
        if constexpr (SPLIT) {
          Bh[nt][kh] = *(const f16x8*)&U[cur][1][bof[nt][kh]];
          Bl[nt][kh] = *(const f16x8*)&U[cur][1][bof[nt][kh] ^ 32];
        } else {
          Bh[nt][kh] = *(const f16x8*)&U[cur][0][bof[nt][kh] ^ 32];
        }
      }
#pragma unroll
    for (int mt = 0; mt < 2; ++mt)
#pragma unroll
      for (int nt = 0; nt < 2; ++nt)
#pragma unroll
        for (int kh = 0; kh < 2; ++kh) {
          acc[mt][nt] = __builtin_amdgcn_mfma_f32_32x32x16_f16(Ah[mt][kh], Bh[nt][kh], acc[mt][nt], 0, 0, 0);
          if constexpr (SPLIT) {
            acc[mt][nt] = __builtin_amdgcn_mfma_f32_32x32x16_f16(Ah[mt][kh], Bl[nt][kh], acc[mt][nt], 0, 0, 0);
            acc[mt][nt] = __builtin_amdgcn_mfma_f32_32x32x16_f16(Al[mt][kh], Bh[nt][kh], acc[mt][nt], 0, 0, 0);
          }
        }
    __builtin_amdgcn_s_barrier();
  }

  float bv[2];
#pragma unroll
  for (int nt = 0; nt < 2; ++nt) bv[nt] = biasq[bn + wc * 64 + nt * 32 + l31];

#pragma unroll
  for (int mt = 0; mt < 2; ++mt) {
#pragma unroll
    for (int reg = 0; reg < 16; ++reg) {
      int rloc = (reg & 3) + 8 * (reg >> 2) + 4 * kq;  // m101 C/D row
      int rowg = bm + wr * 64 + mt * 32 + rloc;
      if (MODE != 0 && rowg >= rows) continue;
      size_t crow = (size_t)((MODE == 0) ? rowg : (r0 + rowg)) * N;
#pragma unroll
      for (int nt = 0; nt < 2; ++nt) {
        float v = acc[mt][nt][reg] + bv[nt];
        if (RELU) v = fmaxf(v, 0.f);
        size_t o = crow + bn + wc * 64 + nt * 32 + l31;
        if (OUTK == 0) {
          ((float*)out0)[o] = v;
        } else if (OUTK == 1) {
          ((unsigned short*)out0)[o] = f2h(v);
        } else {
          unsigned short hi, lo;
          fsplit(v, hi, lo);
          ((unsigned short*)out0)[o] = hi;
          ((unsigned short*)out1)[o] = lo;
        }
      }
    }
  }
}

// ---------------- attention: 16 q-rows/block, MFMA QK^T (3-pass), fp32 softmax/PV ------
__global__ __launch_bounds__(256) void k_attn(const float* __restrict__ qkv,
                                              unsigned short* __restrict__ ohi,
                                              unsigned short* __restrict__ olo) {
  __shared__ float ps[16][256];
  const int qt = blockIdx.x, hh = blockIdx.y, bb = blockIdx.z;
  const int tid = threadIdx.x, w = tid >> 6, lane = tid & 63;
  const int lr = lane & 15, lg = lane >> 4;
  const int t0 = bb * SEQ + qt * 16;

  f16x8 qh[2], ql[2];
#pragma unroll
  for (int kh = 0; kh < 2; ++kh) {
    const float* qb = qkv + (size_t)(t0 + lr) * (3 * DIM) + hh * 64 + kh * 32 + lg * 8;
    split8(*(const float4*)qb, *(const float4*)(qb + 4), qh[kh], ql[kh]);
  }
#pragma unroll
  for (int nt = 0; nt < 4; ++nt) {
    f16x8 kvh[2], kvl[2];
#pragma unroll
    for (int kh = 0; kh < 2; ++kh) {
      const float* kb = qkv + (size_t)(bb * SEQ + w * 64 + nt * 16 + lr) * (3 * DIM)
                        + DIM + hh * 64 + kh * 32 + lg * 8;
      split8(*(const float4*)kb, *(const float4*)(kb + 4), kvh[kh], kvl[kh]);
    }
    f32x4 a = {0.f, 0.f, 0.f, 0.f};
#pragma unroll
    for (int kh = 0; kh < 2; ++kh) {
      a = __builtin_amdgcn_mfma_f32_16x16x32_f16(qh[kh], kvh[kh], a, 0, 0, 0);
      a = __builtin_amdgcn_mfma_f32_16x16x32_f16(qh[kh], kvl[kh], a, 0, 0, 0);
      a = __builtin_amdgcn_mfma_f32_16x16x32_f16(ql[kh], kvh[kh], a, 0, 0, 0);
    }
#pragma unroll
    for (int j = 0; j < 4; ++j)
      ps[lg * 4 + j][w * 64 + nt * 16 + lr] = a[j] * 0.125f;
  }
  __syncthreads();

  for (int rr = w; rr < 16; rr += 4) {
    float v[4];
#pragma unroll
    for (int j = 0; j < 4; ++j) v[j] = ps[rr][lane + 64 * j];
    float m = fmaxf(fmaxf(v[0], v[1]), fmaxf(v[2], v[3]));
    for (int msk = 32; msk; msk >>= 1) m = fmaxf(m, __shfl_xor(m, msk));
    float e[4], sum = 0.f;
#pragma unroll
    for (int j = 0; j < 4; ++j) { e[j] = expf(v[j] - m); sum += e[j]; }
    for (int msk = 32; msk; msk >>= 1) sum += __shfl_xor(sum, msk);
    float inv = 1.0f / sum;
#pragma unroll
    for (int j = 0; j < 4; ++j) ps[rr][lane + 64 * j] = e[j] * inv;
  }
  __syncthreads();

  const int qi0 = w, d = lane;
  float a0 = 0.f, a1 = 0.f, a2 = 0.f, a3 = 0.f;
  const float* vbase = qkv + (size_t)(bb * SEQ) * (3 * DIM) + 2 * DIM + hh * 64 + d;
  for (int k4 = 0; k4 < 64; ++k4) {
    float4 p0 = *(const float4*)&ps[qi0][k4 * 4];
    float4 p1 = *(const float4*)&ps[qi0 + 4][k4 * 4];
    float4 p2 = *(const float4*)&ps[qi0 + 8][k4 * 4];
    float4 p3 = *(const float4*)&ps[qi0 + 12][k4 * 4];
    float q0[4] = {p0.x, p0.y, p0.z, p0.w};
    float q1[4] = {p1.x, p1.y, p1.z, p1.w};
    float q2[4] = {p2.x, p2.y, p2.z, p2.w};
    float q3[4] = {p3.x, p3.y, p3.z, p3.w};
#pragma unroll
    for (int j = 0; j < 4; ++j) {
      float vv = vbase[(size_t)(k4 * 4 + j) * (3 * DIM)];
      a0 += q0[j] * vv; a1 += q1[j] * vv; a2 += q2[j] * vv; a3 += q3[j] * vv;
    }
  }
  float accs[4] = {a0, a1, a2, a3};
#pragma unroll
  for (int j = 0; j < 4; ++j) {
    size_t o = (size_t)(t0 + qi0 + 4 * j) * DIM + hh * 64 + d;
    fsplit(accs[j], ohi[o], olo[o]);
  }
}

// ---------------- block reduce helper ----------------
__device__ __forceinline__ float block_reduce_sum(float v, float* red) {
  const int tid = threadIdx.x;
  red[tid] = v;
  __syncthreads();
  for (int s = 128; s > 0; s >>= 1) {
    if (tid < s) red[tid] += red[tid + s];
    __syncthreads();
  }
  float r = red[0];
  __syncthreads();
  return r;
}

// ---------------- fused: x = LN(xin+add); gate + top-2 + ATOMIC ROUTING ----------
__global__ __launch_bounds__(256) void k_add_ln_gate(const float* __restrict__ xin,
                                                     const float* __restrict__ add,
                                                     const float* __restrict__ g,
                                                     const float* __restrict__ bt,
                                                     const float* __restrict__ gw,
                                                     const float* __restrict__ gb,
                                                     float* __restrict__ xout,
                                                     unsigned short* __restrict__ xhi,
                                                     unsigned short* __restrict__ xlo,
                                                     float* __restrict__ gout,
                                                     int* __restrict__ cnt,
                                                     int* __restrict__ slot_token,
                                                     int* __restrict__ slot_of,
                                                     float* __restrict__ topw) {
  __shared__ float red[256];
  __shared__ float pw[4][NE];
  __shared__ float lgs[NE];
  const int t = blockIdx.x, tid = threadIdx.x;
  const size_t base = (size_t)t * DIM;
  float v[4];
  float s = 0.f;
#pragma unroll
  for (int j = 0; j < 4; ++j) {
    int d = tid + 256 * j;
    v[j] = xin[base + d] + add[base + d];
    s += v[j];
  }
  float mean = block_reduce_sum(s, red) * (1.0f / DIM);
  float s2 = 0.f;
#pragma unroll
  for (int j = 0; j < 4; ++j) { float dv = v[j] - mean; s2 += dv * dv; }
  float var = block_reduce_sum(s2, red) * (1.0f / DIM);
  float rs = rsqrtf(var + 1e-5f);
  float o[4];
#pragma unroll
  for (int j = 0; j < 4; ++j) {
    int d = tid + 256 * j;
    o[j] = (v[j] - mean) * rs * g[d] + bt[d];
    xout[base + d] = o[j];
    fsplit(o[j], xhi[base + d], xlo[base + d]);
  }
  const int wv = tid >> 6, lane = tid & 63;
  float p[NE];
#pragma unroll
  for (int e = 0; e < NE; ++e) {
    float pe = 0.f;
#pragma unroll
    for (int j = 0; j < 4; ++j) pe += o[j] * gw[(size_t)e * DIM + tid + 256 * j];
    for (int m = 32; m; m >>= 1) pe += __shfl_xor(pe, m);
    p[e] = pe;
  }
  if (lane == 0) {
#pragma unroll
    for (int e = 0; e < NE; ++e) pw[wv][e] = p[e];
  }
  __syncthreads();
  if (tid < NE) {
    float l = pw[0][tid] + pw[1][tid] + pw[2][tid] + pw[3][tid] + gb[tid];
    gout[(size_t)t * NE + tid] = l;
    lgs[tid] = l;
  }
  __syncthreads();
  if (tid == 0) {
    int i0 = 0; float v0 = lgs[0];
    for (int i = 1; i < NE; ++i) if (lgs[i] > v0) { v0 = lgs[i]; i0 = i; }
    int i1 = -1; float v1 = -1e30f;
    for (int i = 0; i < NE; ++i) { if (i == i0) continue; if (lgs[i] > v1) { v1 = lgs[i]; i1 = i; } }
    float e1 = expf(v1 - v0);
    float w0 = 1.0f / (1.0f + e1);
    topw[2 * t] = w0; topw[2 * t + 1] = e1 * w0;
    // atomic slot assignment: output is slot-permutation-invariant (each token row
    // is an independent dot product; combine gathers via slot_of), so run-to-run
    // slot ordering differences do not change any output value.
    int idx0 = atomicAdd(&cnt[i0], 1);
    int idx1 = atomicAdd(&cnt[i1], 1);
    slot_token[i0 * CAP + idx0] = t;
    slot_token[i1 * CAP + idx1] = t;
    slot_of[2 * t] = i0 * CAP + idx0;
    slot_of[2 * t + 1] = i1 * CAP + idx1;
  }
}

// ---------------- combine top-2 experts + residual + LN2 (fp32 + hi/lo out) ----------------
__global__ __launch_bounds__(256) void k_moe_combine_ln(const float* __restrict__ xin,
                                                        const float* __restrict__ y,
                                                        const float* __restrict__ topw,
                                                        const int* __restrict__ slot_of,
                                                        const float* __restrict__ g,
                                                        const float* __restrict__ bt,
                                                        float* __restrict__ xout,
                                                        unsigned short* __restrict__ xhi,
                                                        unsigned short* __restrict__ xlo) {
  __shared__ float red[256];
  const int t = blockIdx.x, tid = threadIdx.x;
  const float w0 = topw[2 * t], w1v = topw[2 * t + 1];
  const int s0 = slot_of[2 * t], s1 = slot_of[2 * t + 1];
  const size_t base = (size_t)t * DIM;
  float v[4];
  float s = 0.f;
#pragma unroll
  for (int j = 0; j < 4; ++j) {
    int d = tid + 256 * j;
    v[j] = xin[base + d] + w0 * y[(size_t)s0 * DIM + d] + w1v * y[(size_t)s1 * DIM + d];
    s += v[j];
  }
  float mean = block_reduce_sum(s, red) * (1.0f / DIM);
  float s2 = 0.f;
#pragma unroll
  for (int j = 0; j < 4; ++j) { float dv = v[j] - mean; s2 += dv * dv; }
  float var = block_reduce_sum(s2, red) * (1.0f / DIM);
  float rs = rsqrtf(var + 1e-5f);
#pragma unroll
  for (int j = 0; j < 4; ++j) {
    int d = tid + 256 * j;
    float o = (v[j] - mean) * rs * g[d] + bt[d];
    xout[base + d] = o;
    fsplit(o, xhi[base + d], xlo[base + d]);
  }
}

// ---------------- mean-pool over seq + classifier ----------------
__global__ __launch_bounds__(256) void k_pool_cls(const float* __restrict__ x,
                                                  const float* __restrict__ cw,
                                                  const float* __restrict__ cb,
                                                  float* __restrict__ out) {
  __shared__ float pooled[DIM];
  const int b = blockIdx.x, tid = threadIdx.x;
  float a[4] = {0.f, 0.f, 0.f, 0.f};
  for (int s = 0; s < SEQ; ++s) {
    const float* row = x + (size_t)(b * SEQ + s) * DIM;
#pragma unroll
    for (int j = 0; j < 4; ++j) a[j] += row[tid + 256 * j];
  }
#pragma unroll
  for (int j = 0; j < 4; ++j) pooled[tid + 256 * j] = a[j] * (1.0f / SEQ);
  __syncthreads();
  const int wv = tid >> 6, lane = tid & 63;
  for (int c = wv; c < NCLS; c += 4) {
    float p = 0.f;
    for (int d = lane; d < DIM; d += 64) p += pooled[d] * cw[(size_t)c * DIM + d];
    for (int m = 32; m; m >>= 1) p += __shfl_xor(p, m);
    if (lane == 0) out[b * NCLS + c] = p + cb[c];
  }
}

extern "C" void kernel_launch(void* const* d_in, const int* in_sizes, int n_in,
                              void* d_out, int out_size, void* d_ws, size_t ws_size,
                              hipStream_t stream) {
  const int*   src  = (const int*)  d_in[0];
  const float* emb  = (const float*)d_in[1];
  const float* ipw  = (const float*)d_in[2];
  const float* ipb  = (const float*)d_in[3];
  const float* ow   = (const float*)d_in[4];
  const float* ob   = (const float*)d_in[5];
  const float* ln1g = (const float*)d_in[6];
  const float* ln1b = (const float*)d_in[7];
  const float* ln2g = (const float*)d_in[8];
  const float* ln2b = (const float*)d_in[9];
  const float* gw   = (const float*)d_in[10];
  const float* gb   = (const float*)d_in[11];
  const float* w1   = (const float*)d_in[12];
  const float* b1   = (const float*)d_in[13];
  const float* w2   = (const float*)d_in[14];
  const float* b2   = (const float*)d_in[15];
  const float* cw   = (const float*)d_in[16];
  const float* cb   = (const float*)d_in[17];
  float* out = (float*)d_out;

  char* ws = (char*)d_ws;
  size_t off = 0;
  auto carve = [&](size_t bytes) -> void* {
    void* p = ws + off;
    off += (bytes + 255) & ~(size_t)255;
    return p;
  };
  float*          x      = (float*)carve((size_t)TKN * DIM * 4);
  unsigned short* xhi    = (unsigned short*)carve((size_t)TKN * DIM * 2);
  unsigned short* xlo    = (unsigned short*)carve((size_t)TKN * DIM * 2);
  float*          qkv    = (float*)carve((size_t)TKN * 3 * DIM * 4);
  unsigned short* h_hi   = (unsigned short*)carve((size_t)NE * CAP * HFF * 2);
  unsigned short* h_lo   = (unsigned short*)carve((size_t)NE * CAP * HFF * 2);
  unsigned short* at_hi  = (unsigned short*)carve((size_t)TKN * DIM * 2);
  unsigned short* at_lo  = (unsigned short*)carve((size_t)TKN * DIM * 2);
  float*          proj   = (float*)carve((size_t)TKN * DIM * 4);
  float*          ybuf   = (float*)carve((size_t)NE * CAP * DIM * 4);
  unsigned short* wq_hi  = (unsigned short*)carve((size_t)3 * DIM * DIM * 2);
  unsigned short* wq_lo  = (unsigned short*)carve((size_t)3 * DIM * DIM * 2);
  unsigned short* wo_hi  = (unsigned short*)carve((size_t)DIM * DIM * 2);
  unsigned short* wo_lo  = (unsigned short*)carve((size_t)DIM * DIM * 2);
  unsigned short* wt1_hi = (unsigned short*)carve((size_t)NE * DIM * HFF * 2);
  unsigned short* wt1_lo = (unsigned short*)carve((size_t)NE * DIM * HFF * 2);
  unsigned short* wt2_hi = (unsigned short*)carve((size_t)NE * DIM * HFF * 2);
  unsigned short* wt2_lo = (unsigned short*)carve((size_t)NE * DIM * HFF * 2);
  float* topw       = (float*)carve((size_t)TKN * TOPK * 4);
  int*   slot_token = (int*)  carve((size_t)NE * CAP * 4);
  int*   slot_of    = (int*)  carve((size_t)TKN * TOPK * 4);
  int*   cnt        = (int*)  carve((size_t)NLAYER * NE * 4);

  k_embed<<<TKN, 256, 0, stream>>>(src, emb, x, xhi, xlo, cnt);

  const int n4wq = 3 * DIM * DIM / 4;

  for (int l = 0; l < NLAYER; ++l) {
    const float* ipw_l = ipw + (size_t)l * 3 * DIM * DIM;
    const float* ow_l  = ow  + (size_t)l * DIM * DIM;
    const float* w1_l  = w1  + (size_t)l * NE * DIM * HFF;
    const float* w2_l  = w2  + (size_t)l * NE * HFF * DIM;
    int* cnt_l = cnt + l * NE;
    // routing bit-exact needed for layers 0-2 -> dense 3-pass through l=2;
    // layer-l MoE affects only later gates -> MoE 3-pass for l<2.
    const bool spd = (l < 3);
    const bool spm = (l < 2);

    if (spd)
      k_cvt_split2<true><<<(4 * DIM * DIM) / 1024, 256, 0, stream>>>(
          ipw_l, wq_hi, wq_lo, n4wq, ow_l, wo_hi, wo_lo);
    else
      k_cvt_split2<false><<<(4 * DIM * DIM) / 1024, 256, 0, stream>>>(
          ipw_l, wq_hi, wq_lo, n4wq, ow_l, wo_hi, wo_lo);
    if (spm)
      k_cvt_t2_w12<true><<<dim3(64, 16, 2 * NE), 256, 0, stream>>>(
          w1_l, wt1_hi, wt1_lo, w2_l, wt2_hi, wt2_lo);
    else
      k_cvt_t2_w12<false><<<dim3(64, 16, 2 * NE), 256, 0, stream>>>(
          w1_l, wt1_hi, wt1_lo, w2_l, wt2_hi, wt2_lo);

    if (spd)
      k_mfma_gemm<0, false, 0, true><<<dim3(3 * DIM / 128, TKN / 128), 256, 0, stream>>>(
          xhi, xlo, wq_hi, wq_lo, ipb + (size_t)l * 3 * DIM, qkv, nullptr, TKN, 3 * DIM, DIM, nullptr, nullptr);
    else
      k_mfma_gemm<0, false, 0, false><<<dim3(3 * DIM / 128, TKN / 128), 256, 0, stream>>>(
          xhi, xlo, wq_hi, wq_lo, ipb + (size_t)l * 3 * DIM, qkv, nullptr, TKN, 3 * DIM, DIM, nullptr, nullptr);

    k_attn<<<dim3(SEQ / 16, NHEAD, BATCH), 256, 0, stream>>>(qkv, at_hi, at_lo);

    if (spd)
      k_mfma_gemm<0, false, 0, true><<<dim3(DIM / 128, TKN / 128), 256, 0, stream>>>(
          at_hi, at_lo, wo_hi, wo_lo, ob + (size_t)l * DIM, proj, nullptr, TKN, DIM, DIM, nullptr, nullptr);
    else
      k_mfma_gemm<0, false, 0, false><<<dim3(DIM / 128, TKN / 128), 256, 0, stream>>>(
          at_hi, at_lo, wo_hi, wo_lo, ob + (size_t)l * DIM, proj, nullptr, TKN, DIM, DIM, nullptr, nullptr);

    k_add_ln_gate<<<TKN, 256, 0, stream>>>(x, proj, ln1g + l * DIM, ln1b + l * DIM,
                                           gw + (size_t)l * NE * DIM, gb + l * NE,
                                           x, xhi, xlo,
                                           out + NCLS * BATCH + (size_t)l * TKN * NE,
                                           cnt_l, slot_token, slot_of, topw);

    if (spm)
      k_mfma_gemm<1, true, 2, true><<<dim3(HFF / 128, CAP / 128, NE), 256, 0, stream>>>(
          xhi, xlo, wt1_hi, wt1_lo, b1 + (size_t)l * NE * HFF, h_hi, h_lo, 0, HFF, DIM, slot_token, cnt_l);
    else
      k_mfma_gemm<1, true, 1, false><<<dim3(HFF / 128, CAP / 128, NE), 256, 0, stream>>>(
          xhi, xlo, wt1_hi, wt1_lo, b1 + (size_t)l * NE * HFF, h_hi, nullptr, 0, HFF, DIM, slot_token, cnt_l);

    if (spm)
      k_mfma_gemm<2, false, 0, true><<<dim3(DIM / 128, CAP / 128, NE), 256, 0, stream>>>(
          h_hi, h_lo, wt2_hi, wt2_lo, b2 + (size_t)l * NE * DIM, ybuf, nullptr, 0, DIM, HFF, nullptr, cnt_l);
    else
      k_mfma_gemm<2, false, 0, false><<<dim3(DIM / 128, CAP / 128, NE), 256, 0, stream>>>(
          h_hi, h_lo, wt2_hi, wt2_lo, b2 + (size_t)l * NE * DIM, ybuf, nullptr, 0, DIM, HFF, nullptr, cnt_l);

    k_moe_combine_ln<<<TKN, 256, 0, stream>>>(x, ybuf, topw, slot_of,
                                              ln2g + l * DIM, ln2b + l * DIM, x, xhi, xlo);
  }
  k_pool_cls<<<BATCH, 256, 0, stream>>>(x, cw, cb, out);
}

// Round 11
// 1441.490 us; speedup vs baseline: 1.1226x; 1.1226x over previous
//
#include <hip/hip_runtime.h>
#include <math.h>

#define TKN 2048
#define DIM 1024
#define NHEAD 16
#define HDIM 64
#define HFF 2048
#define NE 8
#define TOPK 2
#define NCLS 10
#define NLAYER 4
#define SEQ 256
#define BATCH 8

typedef __attribute__((ext_vector_type(8))) _Float16 f16x8;
typedef __attribute__((ext_vector_type(4))) float f32x4;
typedef __attribute__((ext_vector_type(16))) float f32x16;
typedef __attribute__((ext_vector_type(8))) unsigned short u16x8;

__device__ __forceinline__ unsigned short f2h(float v) {
  _Float16 h = (_Float16)v;
  return __builtin_bit_cast(unsigned short, h);
}
__device__ __forceinline__ void fsplit(float v, unsigned short& hi, unsigned short& lo) {
  _Float16 h = (_Float16)v;
  hi = __builtin_bit_cast(unsigned short, h);
  lo = f2h(v - (float)h);
}
__device__ __forceinline__ void split8(float4 f0, float4 f1, f16x8& h, f16x8& l) {
  float fv[8] = {f0.x, f0.y, f0.z, f0.w, f1.x, f1.y, f1.z, f1.w};
#pragma unroll
  for (int i = 0; i < 8; ++i) {
    _Float16 hh = (_Float16)fv[i];
    h[i] = hh;
    l[i] = (_Float16)(fv[i] - (float)hh);
  }
}

__device__ __forceinline__ void gload_lds16(const void* g, void* l) {
  __builtin_amdgcn_global_load_lds((__attribute__((address_space(1))) void*)g,
                                   (__attribute__((address_space(3))) void*)l,
                                   16, 0, 0);
}

// ---------------- embed + positional encoding (fp32 + f16 hi/lo out) ----------------
__global__ __launch_bounds__(256) void k_embed(const int* __restrict__ src,
                                               const float* __restrict__ emb,
                                               float* __restrict__ x,
                                               unsigned short* __restrict__ xhi,
                                               unsigned short* __restrict__ xlo) {
  const int t = blockIdx.x;
  const int tid = threadIdx.x;
  const int b = t / SEQ;
  const int tok = src[t];
  const float* erow = emb + (size_t)tok * DIM;
  const size_t base = (size_t)t * DIM;
  const float cexp = -9.210340371976184f / 1024.0f;  // -ln(10000)/D
#pragma unroll
  for (int j = 0; j < 4; ++j) {
    int d = tid + 256 * j;
    int i2 = d & ~1;
    float ang = (float)b * expf((float)i2 * cexp);
    float pe = (d & 1) ? cosf(ang) : sinf(ang);
    float v = erow[d] * 32.0f + pe;
    x[base + d] = v;
    fsplit(v, xhi[base + d], xlo[base + d]);
  }
}

// ---------------- fp32 -> f16 hi/lo planes; two tensors in one dispatch ----------------
template <bool LO>
__global__ __launch_bounds__(256) void k_cvt_split2(const float* __restrict__ inA,
                                                    unsigned short* __restrict__ hA,
                                                    unsigned short* __restrict__ lA,
                                                    int n4A,
                                                    const float* __restrict__ inB,
                                                    unsigned short* __restrict__ hB,
                                                    unsigned short* __restrict__ lB) {
  int i = blockIdx.x * 256 + threadIdx.x;
  const float* in;
  unsigned short *oh, *ol;
  int j;
  if (i < n4A) { in = inA; oh = hA; ol = lA; j = i; }
  else         { in = inB; oh = hB; ol = lB; j = i - n4A; }
  float4 v = ((const float4*)in)[j];
  ushort4 h, l;
  fsplit(v.x, h.x, l.x); fsplit(v.y, h.y, l.y);
  fsplit(v.z, h.z, l.z); fsplit(v.w, h.w, l.w);
  ((ushort4*)oh)[j] = h;
  if (LO) ((ushort4*)ol)[j] = l;
}

// ---------------- transpose + split: in [R][Cc] f32 -> out [Cc][R] f16 hi(/lo) --------
template <bool LO>
__global__ __launch_bounds__(256) void k_cvt_t2(const float* __restrict__ in,
                                                unsigned short* __restrict__ ohi,
                                                unsigned short* __restrict__ olo,
                                                int R, int Cc) {
  __shared__ float ts[64][33];
  const int t = threadIdx.x;
  const int c0 = blockIdx.x * 32, r0 = blockIdx.y * 64;
  const float* ip = in + (size_t)blockIdx.z * R * Cc;
  const size_t obase = (size_t)blockIdx.z * R * Cc;
  const int cc = t & 31, rr0 = t >> 5;
#pragma unroll
  for (int j = 0; j < 8; ++j)
    ts[rr0 + 8 * j][cc] = ip[(size_t)(r0 + rr0 + 8 * j) * Cc + c0 + cc];
  __syncthreads();
  const int c = t >> 3, rch = (t & 7) * 8;
  u16x8 hv, lv;
#pragma unroll
  for (int i = 0; i < 8; ++i) {
    unsigned short hi, lo;
    fsplit(ts[rch + i][c], hi, lo);
    hv[i] = hi; lv[i] = lo;
  }
  size_t o = obase + (size_t)(c0 + c) * R + r0 + rch;
  *(u16x8*)(ohi + o) = hv;
  if (LO) *(u16x8*)(olo + o) = lv;
}

// ---------------- compensated f16 MFMA GEMM (32x32x16), 4-wave blocks ----------
// MODE 0: dense. MODE 1: MoE gather. MODE 2: MoE contig.
// OUTK 0: fp32. 1: f16-hi. 2: f16 hi + lo.  SPLIT: 3-pass compensated.
// Wave computes 64x64 via 2x2 tiles of 32x32x16 (m101 C/D layout:
// col=lane&31, row=(reg&3)+8*(reg>>2)+4*(lane>>5)). LDS [128 rows][8 slots x 16B],
// phys_slot = slot ^ (row&7), realized by pre-swizzled global source.
// Dbuf + counted vmcnt: stage(t+1) -> vmcnt(8|4) -> barrier -> ds_read+MFMA -> barrier.
template <int MODE, bool RELU, int OUTK, bool SPLIT>
__global__ __launch_bounds__(256) void k_mfma_gemm(
    const unsigned short* __restrict__ Ahi, const unsigned short* __restrict__ Alo,
    const unsigned short* __restrict__ Bhi, const unsigned short* __restrict__ Blo,
    const float* __restrict__ bias, void* __restrict__ out0, void* __restrict__ out1,
    int M, int N, int K,
    const int* __restrict__ slot_token, const int* __restrict__ offg) {
  constexpr int NP = SPLIT ? 2 : 1;
  __shared__ unsigned short U[2][NP][128 * 64];
  const int tid = threadIdx.x;
  const int w = tid >> 6, lane = tid & 63;
  const int bm = blockIdx.y * 128, bn = blockIdx.x * 128;
  int r0 = 0, rows = M, e = 0;
  if (MODE != 0) {
    e = blockIdx.z;
    r0 = offg[e];
    rows = offg[e + 1] - r0;
    if (bm >= rows) return;
  }
  const size_t bwb = (size_t)e * K * N;
  const float* biasq = bias + (size_t)e * N;

  // staging: lane covers (row = w*32 + i*8 + (lane>>3), physical slot lane&7)
  const int lrow8 = lane >> 3;
  const int s = (lane & 7) ^ lrow8;
  const int chunk = (s & 3) * 8;
  const unsigned short* sp0[4];
  const unsigned short* sp1[4];
#pragma unroll
  for (int i = 0; i < 4; ++i) {
    int rloc = w * 32 + i * 8 + lrow8;
    int growA;
    if (MODE == 0) {
      growA = bm + rloc;
    } else {
      int rr = bm + rloc;
      if (rr >= rows) rr = rows - 1;
      growA = (MODE == 1) ? slot_token[r0 + rr] : (r0 + rr);
    }
    size_t aoff = (size_t)growA * K + chunk;
    size_t boff = bwb + (size_t)(bn + rloc) * K + chunk;
    if constexpr (SPLIT) {
      sp0[i] = (s < 4 ? Ahi : Alo) + aoff;
      sp1[i] = (s < 4 ? Bhi : Blo) + boff;
    } else {
      sp0[i] = (s < 4) ? (Ahi + aoff) : (Bhi + boff);
      sp1[i] = nullptr;
    }
  }

  f32x16 acc[2][2] = {};
  const int wr = w >> 1, wc = w & 1;
  const int l31 = lane & 31, kq = lane >> 5;
  const int sw = l31 & 7;
  unsigned aof[2][2], bof[2][2];
#pragma unroll
  for (int mt = 0; mt < 2; ++mt)
#pragma unroll
    for (int kh = 0; kh < 2; ++kh)
      aof[mt][kh] = (unsigned)((wr * 64 + mt * 32 + l31) * 64 + (((kh * 2 + kq) ^ sw) * 8));
#pragma unroll
  for (int nt = 0; nt < 2; ++nt)
#pragma unroll
    for (int kh = 0; kh < 2; ++kh)
      bof[nt][kh] = (unsigned)((wc * 64 + nt * 32 + l31) * 64 + (((kh * 2 + kq) ^ sw) * 8));

  // ---- prologue: issue tile-0 stage ----
#pragma unroll
  for (int i = 0; i < 4; ++i) {
    gload_lds16(sp0[i], &U[0][0][(w * 32 + i * 8) * 64]);
    sp0[i] += 32;
    if constexpr (SPLIT) {
      gload_lds16(sp1[i], &U[0][1][(w * 32 + i * 8) * 64]);
      sp1[i] += 32;
    }
  }

  const int NT = K / 32;
#pragma unroll 2
  for (int t = 0; t < NT; ++t) {
    const int cur = t & 1;
    if (t + 1 < NT) {
#pragma unroll
      for (int i = 0; i < 4; ++i) {
        gload_lds16(sp0[i], &U[cur ^ 1][0][(w * 32 + i * 8) * 64]);
        sp0[i] += 32;
        if constexpr (SPLIT) {
          gload_lds16(sp1[i], &U[cur ^ 1][1][(w * 32 + i * 8) * 64]);
          sp1[i] += 32;
        }
      }
      if constexpr (SPLIT)
        asm volatile("s_waitcnt vmcnt(8)" ::: "memory");
      else
        asm volatile("s_waitcnt vmcnt(4)" ::: "memory");
    } else {
      asm volatile("s_waitcnt vmcnt(0)" ::: "memory");
    }
    __builtin_amdgcn_s_barrier();

    f16x8 Ah[2][2], Bh[2][2], Al[2][2], Bl[2][2];
#pragma unroll
    for (int mt = 0; mt < 2; ++mt)
#pragma unroll
      for (int kh = 0; kh < 2; ++kh) {
        Ah[mt][kh] = *(const f16x8*)&U[cur][0][aof[mt][kh]];
        if constexpr (SPLIT) Al[mt][kh] = *(const f16x8*)&U[cur][0][aof[mt][kh] ^ 32];
      }
#pragma unroll
    for (int nt = 0; nt < 2; ++nt)
#pragma unroll
      for (int kh = 0; kh < 2; ++kh) {
        if constexpr (SPLIT) {
          Bh[nt][kh] = *(const f16x8*)&U[cur][1][bof[nt][kh]];
          Bl[nt][kh] = *(const f16x8*)&U[cur][1][bof[nt][kh] ^ 32];
        } else {
          Bh[nt][kh] = *(const f16x8*)&U[cur][0][bof[nt][kh] ^ 32];
        }
      }
#pragma unroll
    for (int mt = 0; mt < 2; ++mt)
#pragma unroll
      for (int nt = 0; nt < 2; ++nt)
#pragma unroll
        for (int kh = 0; kh < 2; ++kh) {
          acc[mt][nt] = __builtin_amdgcn_mfma_f32_32x32x16_f16(Ah[mt][kh], Bh[nt][kh], acc[mt][nt], 0, 0, 0);
          if constexpr (SPLIT) {
            acc[mt][nt] = __builtin_amdgcn_mfma_f32_32x32x16_f16(Ah[mt][kh], Bl[nt][kh], acc[mt][nt], 0, 0, 0);
            acc[mt][nt] = __builtin_amdgcn_mfma_f32_32x32x16_f16(Al[mt][kh], Bh[nt][kh], acc[mt][nt], 0, 0, 0);
          }
        }
    __builtin_amdgcn_s_barrier();
  }

  float bv[2];
#pragma unroll
  for (int nt = 0; nt < 2; ++nt) bv[nt] = biasq[bn + wc * 64 + nt * 32 + l31];

#pragma unroll
  for (int mt = 0; mt < 2; ++mt) {
#pragma unroll
    for (int reg = 0; reg < 16; ++reg) {
      int rloc = (reg & 3) + 8 * (reg >> 2) + 4 * kq;  // m101 C/D row
      int rowg = bm + wr * 64 + mt * 32 + rloc;
      if (MODE != 0 && rowg >= rows) continue;
      size_t crow = (size_t)((MODE == 0) ? rowg : (r0 + rowg)) * N;
#pragma unroll
      for (int nt = 0; nt < 2; ++nt) {
        float v = acc[mt][nt][reg] + bv[nt];
        if (RELU) v = fmaxf(v, 0.f);
        size_t o = crow + bn + wc * 64 + nt * 32 + l31;
        if (OUTK == 0) {
          ((float*)out0)[o] = v;
        } else if (OUTK == 1) {
          ((unsigned short*)out0)[o] = f2h(v);
        } else {
          unsigned short hi, lo;
          fsplit(v, hi, lo);
          ((unsigned short*)out0)[o] = hi;
          ((unsigned short*)out1)[o] = lo;
        }
      }
    }
  }
}

// ---------------- attention: 16 q-rows/block, MFMA QK^T (3-pass), fp32 softmax/PV ------
__global__ __launch_bounds__(256) void k_attn(const float* __restrict__ qkv,
                                              unsigned short* __restrict__ ohi,
                                              unsigned short* __restrict__ olo) {
  __shared__ float ps[16][256];
  const int qt = blockIdx.x, hh = blockIdx.y, bb = blockIdx.z;
  const int tid = threadIdx.x, w = tid >> 6, lane = tid & 63;
  const int lr = lane & 15, lg = lane >> 4;
  const int t0 = bb * SEQ + qt * 16;

  f16x8 qh[2], ql[2];
#pragma unroll
  for (int kh = 0; kh < 2; ++kh) {
    const float* qb = qkv + (size_t)(t0 + lr) * (3 * DIM) + hh * 64 + kh * 32 + lg * 8;
    split8(*(const float4*)qb, *(const float4*)(qb + 4), qh[kh], ql[kh]);
  }
#pragma unroll
  for (int nt = 0; nt < 4; ++nt) {
    f16x8 kvh[2], kvl[2];
#pragma unroll
    for (int kh = 0; kh < 2; ++kh) {
      const float* kb = qkv + (size_t)(bb * SEQ + w * 64 + nt * 16 + lr) * (3 * DIM)
                        + DIM + hh * 64 + kh * 32 + lg * 8;
      split8(*(const float4*)kb, *(const float4*)(kb + 4), kvh[kh], kvl[kh]);
    }
    f32x4 a = {0.f, 0.f, 0.f, 0.f};
#pragma unroll
    for (int kh = 0; kh < 2; ++kh) {
      a = __builtin_amdgcn_mfma_f32_16x16x32_f16(qh[kh], kvh[kh], a, 0, 0, 0);
      a = __builtin_amdgcn_mfma_f32_16x16x32_f16(qh[kh], kvl[kh], a, 0, 0, 0);
      a = __builtin_amdgcn_mfma_f32_16x16x32_f16(ql[kh], kvh[kh], a, 0, 0, 0);
    }
#pragma unroll
    for (int j = 0; j < 4; ++j)
      ps[lg * 4 + j][w * 64 + nt * 16 + lr] = a[j] * 0.125f;
  }
  __syncthreads();

  for (int rr = w; rr < 16; rr += 4) {
    float v[4];
#pragma unroll
    for (int j = 0; j < 4; ++j) v[j] = ps[rr][lane + 64 * j];
    float m = fmaxf(fmaxf(v[0], v[1]), fmaxf(v[2], v[3]));
    for (int msk = 32; msk; msk >>= 1) m = fmaxf(m, __shfl_xor(m, msk));
    float e[4], sum = 0.f;
#pragma unroll
    for (int j = 0; j < 4; ++j) { e[j] = expf(v[j] - m); sum += e[j]; }
    for (int msk = 32; msk; msk >>= 1) sum += __shfl_xor(sum, msk);
    float inv = 1.0f / sum;
#pragma unroll
    for (int j = 0; j < 4; ++j) ps[rr][lane + 64 * j] = e[j] * inv;
  }
  __syncthreads();

  const int qi0 = w, d = lane;
  float a0 = 0.f, a1 = 0.f, a2 = 0.f, a3 = 0.f;
  const float* vbase = qkv + (size_t)(bb * SEQ) * (3 * DIM) + 2 * DIM + hh * 64 + d;
  for (int k4 = 0; k4 < 64; ++k4) {
    float4 p0 = *(const float4*)&ps[qi0][k4 * 4];
    float4 p1 = *(const float4*)&ps[qi0 + 4][k4 * 4];
    float4 p2 = *(const float4*)&ps[qi0 + 8][k4 * 4];
    float4 p3 = *(const float4*)&ps[qi0 + 12][k4 * 4];
    float q0[4] = {p0.x, p0.y, p0.z, p0.w};
    float q1[4] = {p1.x, p1.y, p1.z, p1.w};
    float q2[4] = {p2.x, p2.y, p2.z, p2.w};
    float q3[4] = {p3.x, p3.y, p3.z, p3.w};
#pragma unroll
    for (int j = 0; j < 4; ++j) {
      float vv = vbase[(size_t)(k4 * 4 + j) * (3 * DIM)];
      a0 += q0[j] * vv; a1 += q1[j] * vv; a2 += q2[j] * vv; a3 += q3[j] * vv;
    }
  }
  float accs[4] = {a0, a1, a2, a3};
#pragma unroll
  for (int j = 0; j < 4; ++j) {
    size_t o = (size_t)(t0 + qi0 + 4 * j) * DIM + hh * 64 + d;
    fsplit(accs[j], ohi[o], olo[o]);
  }
}

// ---------------- block reduce helper ----------------
__device__ __forceinline__ float block_reduce_sum(float v, float* red) {
  const int tid = threadIdx.x;
  red[tid] = v;
  __syncthreads();
  for (int s = 128; s > 0; s >>= 1) {
    if (tid < s) red[tid] += red[tid + s];
    __syncthreads();
  }
  float r = red[0];
  __syncthreads();
  return r;
}

// ---------------- fused: x = LN(xin+add); gate logits + top-2 from registers ----------
__global__ __launch_bounds__(256) void k_add_ln_gate(const float* __restrict__ xin,
                                                     const float* __restrict__ add,
                                                     const float* __restrict__ g,
                                                     const float* __restrict__ bt,
                                                     const float* __restrict__ gw,
                                                     const float* __restrict__ gb,
                                                     float* __restrict__ xout,
                                                     unsigned short* __restrict__ xhi,
                                                     unsigned short* __restrict__ xlo,
                                                     float* __restrict__ gout,
                                                     int* __restrict__ topi,
                                                     float* __restrict__ topw) {
  __shared__ float red[256];
  __shared__ float pw[4][NE];
  __shared__ float lgs[NE];
  const int t = blockIdx.x, tid = threadIdx.x;
  const size_t base = (size_t)t * DIM;
  float v[4];
  float s = 0.f;
#pragma unroll
  for (int j = 0; j < 4; ++j) {
    int d = tid + 256 * j;
    v[j] = xin[base + d] + add[base + d];
    s += v[j];
  }
  float mean = block_reduce_sum(s, red) * (1.0f / DIM);
  float s2 = 0.f;
#pragma unroll
  for (int j = 0; j < 4; ++j) { float dv = v[j] - mean; s2 += dv * dv; }
  float var = block_reduce_sum(s2, red) * (1.0f / DIM);
  float rs = rsqrtf(var + 1e-5f);
  float o[4];
#pragma unroll
  for (int j = 0; j < 4; ++j) {
    int d = tid + 256 * j;
    o[j] = (v[j] - mean) * rs * g[d] + bt[d];
    xout[base + d] = o[j];
    fsplit(o[j], xhi[base + d], xlo[base + d]);
  }
  const int wv = tid >> 6, lane = tid & 63;
  float p[NE];
#pragma unroll
  for (int e = 0; e < NE; ++e) {
    float pe = 0.f;
#pragma unroll
    for (int j = 0; j < 4; ++j) pe += o[j] * gw[(size_t)e * DIM + tid + 256 * j];
    for (int m = 32; m; m >>= 1) pe += __shfl_xor(pe, m);
    p[e] = pe;
  }
  if (lane == 0) {
#pragma unroll
    for (int e = 0; e < NE; ++e) pw[wv][e] = p[e];
  }
  __syncthreads();
  if (tid < NE) {
    float l = pw[0][tid] + pw[1][tid] + pw[2][tid] + pw[3][tid] + gb[tid];
    gout[(size_t)t * NE + tid] = l;
    lgs[tid] = l;
  }
  __syncthreads();
  if (tid == 0) {
    int i0 = 0; float v0 = lgs[0];
    for (int i = 1; i < NE; ++i) if (lgs[i] > v0) { v0 = lgs[i]; i0 = i; }
    int i1 = -1; float v1 = -1e30f;
    for (int i = 0; i < NE; ++i) { if (i == i0) continue; if (lgs[i] > v1) { v1 = lgs[i]; i1 = i; } }
    float e1 = expf(v1 - v0);
    float w0 = 1.0f / (1.0f + e1);
    topi[2 * t] = i0; topi[2 * t + 1] = i1;
    topw[2 * t] = w0; topw[2 * t + 1] = e1 * w0;
  }
}

// ---------------- deterministic routing build ----------------
__global__ __launch_bounds__(512) void k_route(const int* __restrict__ topi,
                                               int* __restrict__ offg,
                                               int* __restrict__ slot_token,
                                               int* __restrict__ slot_of) {
  __shared__ int cnt_s[NE];
  __shared__ int off_s[NE + 1];
  const int tid = threadIdx.x;
  const int w = tid >> 6, lane = tid & 63;
  int c = 0;
  for (int i = lane; i < TKN * TOPK; i += 64) c += (topi[i] == w) ? 1 : 0;
  for (int m = 32; m; m >>= 1) c += __shfl_xor(c, m);
  if (lane == 0) cnt_s[w] = c;
  __syncthreads();
  if (tid == 0) {
    off_s[0] = 0;
    for (int e2 = 0; e2 < NE; ++e2) off_s[e2 + 1] = off_s[e2] + cnt_s[e2];
    for (int e2 = 0; e2 <= NE; ++e2) offg[e2] = off_s[e2];
  }
  __syncthreads();
  int base = off_s[w];
  for (int i0 = 0; i0 < TKN * TOPK; i0 += 64) {
    int i = i0 + lane;
    bool mm = (topi[i] == w);
    unsigned long long mask = __ballot(mm ? 1 : 0);
    int rank = __popcll(mask & ((1ull << lane) - 1ull));
    if (mm) {
      int slot = base + rank;
      slot_token[slot] = i >> 1;
      slot_of[i] = slot;
    }
    base += __popcll(mask);
  }
}

// ---------------- combine top-2 experts + residual + LN2 (fp32 + hi/lo out) ----------------
__global__ __launch_bounds__(256) void k_moe_combine_ln(const float* __restrict__ xin,
                                                        const float* __restrict__ y,
                                                        const float* __restrict__ topw,
                                                        const int* __restrict__ slot_of,
                                                        const float* __restrict__ g,
                                                        const float* __restrict__ bt,
                                                        float* __restrict__ xout,
                                                        unsigned short* __restrict__ xhi,
                                                        unsigned short* __restrict__ xlo) {
  __shared__ float red[256];
  const int t = blockIdx.x, tid = threadIdx.x;
  const float w0 = topw[2 * t], w1v = topw[2 * t + 1];
  const int s0 = slot_of[2 * t], s1 = slot_of[2 * t + 1];
  const size_t base = (size_t)t * DIM;
  float v[4];
  float s = 0.f;
#pragma unroll
  for (int j = 0; j < 4; ++j) {
    int d = tid + 256 * j;
    v[j] = xin[base + d] + w0 * y[(size_t)s0 * DIM + d] + w1v * y[(size_t)s1 * DIM + d];
    s += v[j];
  }
  float mean = block_reduce_sum(s, red) * (1.0f / DIM);
  float s2 = 0.f;
#pragma unroll
  for (int j = 0; j < 4; ++j) { float dv = v[j] - mean; s2 += dv * dv; }
  float var = block_reduce_sum(s2, red) * (1.0f / DIM);
  float rs = rsqrtf(var + 1e-5f);
#pragma unroll
  for (int j = 0; j < 4; ++j) {
    int d = tid + 256 * j;
    float o = (v[j] - mean) * rs * g[d] + bt[d];
    xout[base + d] = o;
    fsplit(o, xhi[base + d], xlo[base + d]);
  }
}

// ---------------- mean-pool over seq + classifier ----------------
__global__ __launch_bounds__(256) void k_pool_cls(const float* __restrict__ x,
                                                  const float* __restrict__ cw,
                                                  const float* __restrict__ cb,
                                                  float* __restrict__ out) {
  __shared__ float pooled[DIM];
  const int b = blockIdx.x, tid = threadIdx.x;
  float a[4] = {0.f, 0.f, 0.f, 0.f};
  for (int s = 0; s < SEQ; ++s) {
    const float* row = x + (size_t)(b * SEQ + s) * DIM;
#pragma unroll
    for (int j = 0; j < 4; ++j) a[j] += row[tid + 256 * j];
  }
#pragma unroll
  for (int j = 0; j < 4; ++j) pooled[tid + 256 * j] = a[j] * (1.0f / SEQ);
  __syncthreads();
  const int wv = tid >> 6, lane = tid & 63;
  for (int c = wv; c < NCLS; c += 4) {
    float p = 0.f;
    for (int d = lane; d < DIM; d += 64) p += pooled[d] * cw[(size_t)c * DIM + d];
    for (int m = 32; m; m >>= 1) p += __shfl_xor(p, m);
    if (lane == 0) out[b * NCLS + c] = p + cb[c];
  }
}

extern "C" void kernel_launch(void* const* d_in, const int* in_sizes, int n_in,
                              void* d_out, int out_size, void* d_ws, size_t ws_size,
                              hipStream_t stream) {
  const int*   src  = (const int*)  d_in[0];
  const float* emb  = (const float*)d_in[1];
  const float* ipw  = (const float*)d_in[2];
  const float* ipb  = (const float*)d_in[3];
  const float* ow   = (const float*)d_in[4];
  const float* ob   = (const float*)d_in[5];
  const float* ln1g = (const float*)d_in[6];
  const float* ln1b = (const float*)d_in[7];
  const float* ln2g = (const float*)d_in[8];
  const float* ln2b = (const float*)d_in[9];
  const float* gw   = (const float*)d_in[10];
  const float* gb   = (const float*)d_in[11];
  const float* w1   = (const float*)d_in[12];
  const float* b1   = (const float*)d_in[13];
  const float* w2   = (const float*)d_in[14];
  const float* b2   = (const float*)d_in[15];
  const float* cw   = (const float*)d_in[16];
  const float* cb   = (const float*)d_in[17];
  float* out = (float*)d_out;

  char* ws = (char*)d_ws;
  size_t off = 0;
  auto carve = [&](size_t bytes) -> void* {
    void* p = ws + off;
    off += (bytes + 255) & ~(size_t)255;
    return p;
  };
  float*          x     = (float*)carve((size_t)TKN * DIM * 4);
  unsigned short* xhi   = (unsigned short*)carve((size_t)TKN * DIM * 2);
  unsigned short* xlo   = (unsigned short*)carve((size_t)TKN * DIM * 2);
  char*           bufQ  = (char*)carve((size_t)2 * TKN * TOPK * HFF * 2);
  float*          qkv   = (float*)bufQ;
  unsigned short* h_hi  = (unsigned short*)bufQ;
  unsigned short* h_lo  = (unsigned short*)(bufQ + (size_t)TKN * TOPK * HFF * 2);
  unsigned short* at_hi = (unsigned short*)carve((size_t)TKN * DIM * 2);
  unsigned short* at_lo = (unsigned short*)carve((size_t)TKN * DIM * 2);
  char*           bufP  = (char*)carve((size_t)TKN * TOPK * DIM * 4);
  float*          proj  = (float*)bufP;
  float*          ybuf  = (float*)bufP;
  unsigned short* wq_hi = (unsigned short*)carve((size_t)3 * DIM * DIM * 2);
  unsigned short* wq_lo = (unsigned short*)carve((size_t)3 * DIM * DIM * 2);
  unsigned short* wo_hi = (unsigned short*)carve((size_t)DIM * DIM * 2);
  unsigned short* wo_lo = (unsigned short*)carve((size_t)DIM * DIM * 2);
  unsigned short* wt_hi = (unsigned short*)carve((size_t)NE * DIM * HFF * 2);
  unsigned short* wt_lo = (unsigned short*)carve((size_t)NE * DIM * HFF * 2);
  float* topw       = (float*)carve((size_t)TKN * TOPK * 4);
  int*   topi       = (int*)  carve((size_t)TKN * TOPK * 4);
  int*   slot_token = (int*)  carve((size_t)TKN * TOPK * 4);
  int*   slot_of    = (int*)  carve((size_t)TKN * TOPK * 4);
  int*   offg       = (int*)  carve(64);

  k_embed<<<TKN, 256, 0, stream>>>(src, emb, x, xhi, xlo);

  const int n4wq = 3 * DIM * DIM / 4;  // float4 units in ipw slice

  for (int l = 0; l < NLAYER; ++l) {
    const float* ipw_l = ipw + (size_t)l * 3 * DIM * DIM;
    const float* ow_l  = ow  + (size_t)l * DIM * DIM;
    const float* w1_l  = w1  + (size_t)l * NE * DIM * HFF;
    const float* w2_l  = w2  + (size_t)l * NE * HFF * DIM;
    // routing bit-exact needed for layers 0-2 -> dense 3-pass through l=2;
    // layer-l MoE affects only later gates -> MoE 3-pass for l<2.
    const bool spd = (l < 3);
    const bool spm = (l < 2);

    if (spd)
      k_cvt_split2<true><<<(4 * DIM * DIM) / 1024, 256, 0, stream>>>(
          ipw_l, wq_hi, wq_lo, n4wq, ow_l, wo_hi, wo_lo);
    else
      k_cvt_split2<false><<<(4 * DIM * DIM) / 1024, 256, 0, stream>>>(
          ipw_l, wq_hi, wq_lo, n4wq, ow_l, wo_hi, wo_lo);
    if (spm)
      k_cvt_t2<true><<<dim3(HFF / 32, DIM / 64, NE), 256, 0, stream>>>(w1_l, wt_hi, wt_lo, DIM, HFF);
    else
      k_cvt_t2<false><<<dim3(HFF / 32, DIM / 64, NE), 256, 0, stream>>>(w1_l, wt_hi, wt_lo, DIM, HFF);

    if (spd)
      k_mfma_gemm<0, false, 0, true><<<dim3(3 * DIM / 128, TKN / 128), 256, 0, stream>>>(
          xhi, xlo, wq_hi, wq_lo, ipb + (size_t)l * 3 * DIM, qkv, nullptr, TKN, 3 * DIM, DIM, nullptr, nullptr);
    else
      k_mfma_gemm<0, false, 0, false><<<dim3(3 * DIM / 128, TKN / 128), 256, 0, stream>>>(
          xhi, xlo, wq_hi, wq_lo, ipb + (size_t)l * 3 * DIM, qkv, nullptr, TKN, 3 * DIM, DIM, nullptr, nullptr);

    k_attn<<<dim3(SEQ / 16, NHEAD, BATCH), 256, 0, stream>>>(qkv, at_hi, at_lo);

    if (spd)
      k_mfma_gemm<0, false, 0, true><<<dim3(DIM / 128, TKN / 128), 256, 0, stream>>>(
          at_hi, at_lo, wo_hi, wo_lo, ob + (size_t)l * DIM, proj, nullptr, TKN, DIM, DIM, nullptr, nullptr);
    else
      k_mfma_gemm<0, false, 0, false><<<dim3(DIM / 128, TKN / 128), 256, 0, stream>>>(
          at_hi, at_lo, wo_hi, wo_lo, ob + (size_t)l * DIM, proj, nullptr, TKN, DIM, DIM, nullptr, nullptr);

    k_add_ln_gate<<<TKN, 256, 0, stream>>>(x, proj, ln1g + l * DIM, ln1b + l * DIM,
                                           gw + (size_t)l * NE * DIM, gb + l * NE,
                                           x, xhi, xlo,
                                           out + NCLS * BATCH + (size_t)l * TKN * NE, topi, topw);
    k_route<<<1, 512, 0, stream>>>(topi, offg, slot_token, slot_of);

    if (spm)
      k_mfma_gemm<1, true, 2, true><<<dim3(HFF / 128, TKN * TOPK / 128, NE), 256, 0, stream>>>(
          xhi, xlo, wt_hi, wt_lo, b1 + (size_t)l * NE * HFF, h_hi, h_lo, 0, HFF, DIM, slot_token, offg);
    else
      k_mfma_gemm<1, true, 1, false><<<dim3(HFF / 128, TKN * TOPK / 128, NE), 256, 0, stream>>>(
          xhi, xlo, wt_hi, wt_lo, b1 + (size_t)l * NE * HFF, h_hi, nullptr, 0, HFF, DIM, slot_token, offg);

    if (spm)
      k_cvt_t2<true><<<dim3(DIM / 32, HFF / 64, NE), 256, 0, stream>>>(w2_l, wt_hi, wt_lo, HFF, DIM);
    else
      k_cvt_t2<false><<<dim3(DIM / 32, HFF / 64, NE), 256, 0, stream>>>(w2_l, wt_hi, wt_lo, HFF, DIM);

    if (spm)
      k_mfma_gemm<2, false, 0, true><<<dim3(DIM / 128, TKN * TOPK / 128, NE), 256, 0, stream>>>(
          h_hi, h_lo, wt_hi, wt_lo, b2 + (size_t)l * NE * DIM, ybuf, nullptr, 0, DIM, HFF, nullptr, offg);
    else
      k_mfma_gemm<2, false, 0, false><<<dim3(DIM / 128, TKN * TOPK / 128, NE), 256, 0, stream>>>(
          h_hi, h_lo, wt_hi, wt_lo, b2 + (size_t)l * NE * DIM, ybuf, nullptr, 0, DIM, HFF, nullptr, offg);

    k_moe_combine_ln<<<TKN, 256, 0, stream>>>(x, ybuf, topw, slot_of,
                                              ln2g + l * DIM, ln2b + l * DIM, x, xhi, xlo);
  }
  k_pool_cls<<<BATCH, 256, 0, stream>>>(x, cw, cb, out);
}